// Round 3
// baseline (1401.128 us; speedup 1.0000x reference)
//
#include <hip/hip_runtime.h>

// DistanceScaledDotAttention: B=4,H=8,S=2048,D=64
//   scores = (Q K^T / 8) * dist; masked -> -1e10; softmax; ctx = P V
//   outputs: ctx [4,8,2048,64] fp32, attn [4,8,2048,2048] fp32 (concat in d_out)
//
// v3 structure (v2 + distance-1 register software pipeline):
//   prep_kernel: K,V -> f16 MFMA-fragment planes in workspace (16 MiB).
//   dsda_kernel: one block = 8 q-rows of one (b,h); 32 k-tiles of 64.
//     - K/V fragments + dist/mask for tile kt+1 are prefetched into registers
//       at the top of tile kt (HBM ~900cyc latency hidden under a full iter).
//     - in-loop barrier is raw s_barrier + lgkmcnt(0) only (no vmcnt drain ->
//       prefetch loads stay in flight across the barrier).
//     - e_smem XOR-swizzled (byte ^= row<<4): PV ds_read_b128 conflict-free.
//     - dist/mask loads + attn stores nontemporal (touch-once stream).

typedef float v4f __attribute__((ext_vector_type(4)));
typedef _Float16 v8h __attribute__((ext_vector_type(8)));

#define SEQ 2048
#define DH  64
#define TQ  8
#define TK  64
#define NKT (SEQ / TK)   // 32
#define NBH 32
#define PLANE ((size_t)NBH * NKT * 256)   // v8h elements per fragment plane (4 MiB)

__device__ inline v8h cvt8(float4 a, float4 b) {
    v8h h;
    h[0] = (_Float16)a.x; h[1] = (_Float16)a.y; h[2] = (_Float16)a.z; h[3] = (_Float16)a.w;
    h[4] = (_Float16)b.x; h[5] = (_Float16)b.y; h[6] = (_Float16)b.z; h[7] = (_Float16)b.w;
    return h;
}

// ---- prep: build fragment planes --------------------------------------------
// Kf0[bh][kt][tid] = { (f16)K[bh][kt*64 + 16*wave + l16][quad*8 + j] , j=0..7 }
// Kf1: d += 32.
// Vf0[bh][kt][tid] = { (f16)V[bh][kt*64 + quad*8 + j][wave*16 + l16] , j=0..7 }
// Vf1: k += 32.
__global__ __launch_bounds__(256)
void prep_kernel(const float* __restrict__ Kg, const float* __restrict__ Vg,
                 v8h* __restrict__ W)
{
    const int kt   = blockIdx.x;
    const int bh   = blockIdx.y;
    const int tid  = (int)threadIdx.x;
    const int wave = tid >> 6;
    const int lane = tid & 63;
    const int quad = lane >> 4;
    const int l16  = lane & 15;
    const int k0   = kt * TK;

    const size_t bh_off = (size_t)bh * SEQ * DH;
    const size_t fi     = ((size_t)bh * NKT + kt) * 256 + tid;

    const float* kr = Kg + bh_off + (size_t)(k0 + wave * 16 + l16) * DH + quad * 8;
    W[fi]         = cvt8(((const float4*)kr)[0], ((const float4*)kr)[1]);
    W[PLANE + fi] = cvt8(((const float4*)(kr + 32))[0], ((const float4*)(kr + 32))[1]);

    const float* vc = Vg + bh_off + (size_t)(k0 + quad * 8) * DH + wave * 16 + l16;
    v8h v0, v1;
#pragma unroll
    for (int j = 0; j < 8; ++j) {
        v0[j] = (_Float16)vc[(size_t)j * DH];
        v1[j] = (_Float16)vc[(size_t)(j + 32) * DH];
    }
    W[2 * PLANE + fi] = v0;
    W[3 * PLANE + fi] = v1;
}

// ---- main -------------------------------------------------------------------
template<bool USE_WS>
__global__ __launch_bounds__(256, 4)
void dsda_kernel(const float* __restrict__ Qg, const float* __restrict__ Kg,
                 const float* __restrict__ Vg, const float* __restrict__ distg,
                 const int* __restrict__ maskg, const v8h* __restrict__ W,
                 float* __restrict__ ctx_out, float* __restrict__ attn_out)
{
    const int qt   = blockIdx.x;    // 0..255 (fast dim: same bh streams together -> L2 reuse of frags)
    const int bh   = blockIdx.y;    // 0..31
    const int q0   = qt * TQ;
    const int tid  = (int)threadIdx.x;
    const int wave = tid >> 6;
    const int lane = tid & 63;
    const int quad = lane >> 4;
    const int l16  = lane & 15;

    // e_smem: swizzled addressing, byte(row,col) = row*4096 + ((col*2) ^ (row<<4))
    __shared__ __align__(16) _Float16 e_smem[TQ * SEQ];   // 32 KB
    __shared__ float rs[TQ];
    if (tid < TQ) rs[tid] = 0.f;

    const size_t bh_off  = (size_t)bh * SEQ;
    const float* Qb = Qg + bh_off * DH;
    const float* Kb = Kg + bh_off * DH;
    const float* Vb = Vg + bh_off * DH;
    const size_t dm_base = (bh_off + (size_t)q0) * SEQ;

    // Q A-fragments (persist): A[m=l16][k = s*32 + quad*8 + j]
    v8h aq0 = {}, aq1 = {};
    if (l16 < TQ) {
        const float* qrow = Qb + (size_t)(q0 + l16) * DH;
        const float4* p0 = (const float4*)(qrow + quad * 8);
        const float4* p1 = (const float4*)(qrow + 32 + quad * 8);
        aq0 = cvt8(p0[0], p0[1]);
        aq1 = cvt8(p1[0], p1[1]);
    }

    v4f acc_pv = {0.f, 0.f, 0.f, 0.f};      // ctx acc: [row=quad*4+r][d=wave*16+l16]
    float rsum[4] = {0.f, 0.f, 0.f, 0.f};
    const size_t fbase = (size_t)bh * NKT * 256 + tid;

#define LOAD_FRAGS(KT, B0, B1, B2, B3) do {                                   \
        const size_t fi_ = fbase + (size_t)(KT) * 256;                        \
        B0 = W[fi_]; B1 = W[PLANE + fi_];                                     \
        B2 = W[2 * PLANE + fi_]; B3 = W[3 * PLANE + fi_];                     \
    } while (0)

#define LOAD_DM(KT, DV, MV) do {                                              \
        if (quad < 2) {                                                       \
            const int kc_ = (KT) * TK + wave * 16 + l16;                      \
            _Pragma("unroll")                                                 \
            for (int r_ = 0; r_ < 4; ++r_) {                                  \
                const size_t idx_ = dm_base + (size_t)(quad * 4 + r_) * SEQ + kc_; \
                DV[r_] = __builtin_nontemporal_load(&distg[idx_]);            \
                MV[r_] = __builtin_nontemporal_load(&maskg[idx_]);            \
            }                                                                 \
        }                                                                     \
    } while (0)

    if constexpr (USE_WS) {
        // ---- prologue: tile 0 in flight ----
        v8h bk0_c, bk1_c, bv0_c, bv1_c;
        float dv_c[4] = {}; int mv_c[4] = {};
        LOAD_FRAGS(0, bk0_c, bk1_c, bv0_c, bv1_c);
        LOAD_DM(0, dv_c, mv_c);

#pragma unroll 2
        for (int kt = 0; kt < NKT; ++kt) {
            const int k0 = kt * TK;

            // ---- prefetch tile kt+1 (clamped; values unused on last iter) ----
            const int ktn = (kt + 1 < NKT) ? kt + 1 : 0;
            v8h bk0_n, bk1_n, bv0_n, bv1_n;
            float dv_n[4] = {}; int mv_n[4] = {};
            LOAD_FRAGS(ktn, bk0_n, bk1_n, bv0_n, bv1_n);
            LOAD_DM(ktn, dv_n, mv_n);

            // ---- QK^T: wave w owns k-cols [k0+16w, +16) ----
            v4f accs = {0.f, 0.f, 0.f, 0.f};
            accs = __builtin_amdgcn_mfma_f32_16x16x32_f16(aq0, bk0_c, accs, 0, 0, 0);
            accs = __builtin_amdgcn_mfma_f32_16x16x32_f16(aq1, bk1_c, accs, 0, 0, 0);

            // ---- epilogue: scale, mask, exp; stash e (swizzled) + row-sums ----
            if (quad < 2) {
                const int kc = k0 + wave * 16 + l16;
#pragma unroll
                for (int r = 0; r < 4; ++r) {
                    const int row = quad * 4 + r;
                    const float sc = accs[r] * 0.125f * dv_c[r];
                    const float e  = mv_c[r] ? 0.f : __expf(sc);
                    rsum[r] += e;
                    *(_Float16*)((char*)e_smem + (row * (SEQ * 2) + ((kc * 2) ^ (row << 4)))) = (_Float16)e;
                }
            }

            // ---- barrier: LDS visibility only (keep prefetch vmem in flight) ----
            asm volatile("s_waitcnt lgkmcnt(0)" ::: "memory");
            __builtin_amdgcn_s_barrier();
            asm volatile("" ::: "memory");

            // ---- PV: A[m=l16][k]=e (swizzled b128, conflict-free) ----
            v8h ap0 = {}, ap1 = {};
            if (l16 < TQ) {
                const int b0 = l16 * (SEQ * 2) + (((k0 + quad * 8) * 2) ^ (l16 << 4));
                const int b1 = l16 * (SEQ * 2) + (((k0 + 32 + quad * 8) * 2) ^ (l16 << 4));
                ap0 = *(const v8h*)((const char*)e_smem + b0);
                ap1 = *(const v8h*)((const char*)e_smem + b1);
            }
            acc_pv = __builtin_amdgcn_mfma_f32_16x16x32_f16(ap0, bv0_c, acc_pv, 0, 0, 0);
            acc_pv = __builtin_amdgcn_mfma_f32_16x16x32_f16(ap1, bv1_c, acc_pv, 0, 0, 0);

            // ---- rotate double buffer (copies elided by unroll-2) ----
            bk0_c = bk0_n; bk1_c = bk1_n; bv0_c = bv0_n; bv1_c = bv1_n;
#pragma unroll
            for (int r = 0; r < 4; ++r) { dv_c[r] = dv_n[r]; mv_c[r] = mv_n[r]; }
        }
    } else {
        // ---- fallback path (no workspace): direct loads, no pipeline ----
        for (int kt = 0; kt < NKT; ++kt) {
            const int k0 = kt * TK;
            v8h bk0, bk1, bv0, bv1;
            const float* kr = Kb + (size_t)(k0 + wave * 16 + l16) * DH + quad * 8;
            bk0 = cvt8(((const float4*)kr)[0], ((const float4*)kr)[1]);
            bk1 = cvt8(((const float4*)(kr + 32))[0], ((const float4*)(kr + 32))[1]);
            const float* vc = Vb + (size_t)(k0 + quad * 8) * DH + wave * 16 + l16;
#pragma unroll
            for (int j = 0; j < 8; ++j) {
                bv0[j] = (_Float16)vc[(size_t)j * DH];
                bv1[j] = (_Float16)vc[(size_t)(j + 32) * DH];
            }
            float dv[4] = {}; int mv[4] = {};
            LOAD_DM(kt, dv, mv);

            v4f accs = {0.f, 0.f, 0.f, 0.f};
            accs = __builtin_amdgcn_mfma_f32_16x16x32_f16(aq0, bk0, accs, 0, 0, 0);
            accs = __builtin_amdgcn_mfma_f32_16x16x32_f16(aq1, bk1, accs, 0, 0, 0);

            if (quad < 2) {
                const int kc = k0 + wave * 16 + l16;
#pragma unroll
                for (int r = 0; r < 4; ++r) {
                    const int row = quad * 4 + r;
                    const float sc = accs[r] * 0.125f * dv[r];
                    const float e  = mv[r] ? 0.f : __expf(sc);
                    rsum[r] += e;
                    *(_Float16*)((char*)e_smem + (row * (SEQ * 2) + ((kc * 2) ^ (row << 4)))) = (_Float16)e;
                }
            }
            __syncthreads();

            v8h ap0 = {}, ap1 = {};
            if (l16 < TQ) {
                const int b0 = l16 * (SEQ * 2) + (((k0 + quad * 8) * 2) ^ (l16 << 4));
                const int b1 = l16 * (SEQ * 2) + (((k0 + 32 + quad * 8) * 2) ^ (l16 << 4));
                ap0 = *(const v8h*)((const char*)e_smem + b0);
                ap1 = *(const v8h*)((const char*)e_smem + b1);
            }
            acc_pv = __builtin_amdgcn_mfma_f32_16x16x32_f16(ap0, bv0, acc_pv, 0, 0, 0);
            acc_pv = __builtin_amdgcn_mfma_f32_16x16x32_f16(ap1, bv1, acc_pv, 0, 0, 0);
        }
    }

    // ---- reduce row sums: sum over l16 within quad, then across waves ----
    if (quad < 2) {
#pragma unroll
        for (int r = 0; r < 4; ++r) {
            float v = rsum[r];
            v += __shfl_xor(v, 1);
            v += __shfl_xor(v, 2);
            v += __shfl_xor(v, 4);
            v += __shfl_xor(v, 8);
            if (l16 == 0) atomicAdd(&rs[quad * 4 + r], v);
        }
    }
    __syncthreads();

    // ---- context write ----
    if (quad < 2) {
#pragma unroll
        for (int r = 0; r < 4; ++r) {
            const int row = quad * 4 + r;
            const float inv = 1.f / rs[row];
            ctx_out[(bh_off + (size_t)(q0 + row)) * DH + wave * 16 + l16] = acc_pv[r] * inv;
        }
    }

    // ---- attn write: normalized e, nontemporal ext-vector stores ----
    {
        const int r  = tid >> 5;        // 0..7
        const int tt = tid & 31;        // 0..31
        const float invr = 1.f / rs[r];
        float* arow = attn_out + dm_base + (size_t)r * SEQ;
#pragma unroll
        for (int c = 0; c < 8; ++c) {
            const int col = c * 256 + tt * 8;
            const int b   = r * (SEQ * 2) + ((col * 2) ^ (r << 4));
            v8h e8 = *(const v8h*)((const char*)e_smem + b);
            v4f f0, f1;
            f0[0] = (float)e8[0] * invr; f0[1] = (float)e8[1] * invr;
            f0[2] = (float)e8[2] * invr; f0[3] = (float)e8[3] * invr;
            f1[0] = (float)e8[4] * invr; f1[1] = (float)e8[5] * invr;
            f1[2] = (float)e8[6] * invr; f1[3] = (float)e8[7] * invr;
            __builtin_nontemporal_store(f0, (v4f*)(arow + col));
            __builtin_nontemporal_store(f1, (v4f*)(arow + col) + 1);
        }
    }
}

extern "C" void kernel_launch(void* const* d_in, const int* in_sizes, int n_in,
                              void* d_out, int out_size, void* d_ws, size_t ws_size,
                              hipStream_t stream) {
    const float* Q    = (const float*)d_in[0];
    const float* K    = (const float*)d_in[1];
    const float* V    = (const float*)d_in[2];
    const float* dist = (const float*)d_in[3];
    const int*   mask = (const int*)d_in[4];

    float* ctx  = (float*)d_out;                                  // 4*8*2048*64
    float* attn = (float*)d_out + (size_t)4 * 8 * 2048 * 64;      // 4*8*2048*2048

    const size_t need = 4 * PLANE * sizeof(v8h);                  // 16 MiB
    if (d_ws != nullptr && ws_size >= need) {
        hipLaunchKernelGGL(prep_kernel, dim3(NKT, NBH), dim3(256), 0, stream,
                           K, V, (v8h*)d_ws);
        hipLaunchKernelGGL((dsda_kernel<true>), dim3(SEQ / TQ, NBH), dim3(256), 0, stream,
                           Q, K, V, dist, mask, (const v8h*)d_ws, ctx, attn);
    } else {
        hipLaunchKernelGGL((dsda_kernel<false>), dim3(SEQ / TQ, NBH), dim3(256), 0, stream,
                           Q, K, V, dist, mask, (const v8h*)nullptr, ctx, attn);
    }
}

// Round 4
// 1317.772 us; speedup vs baseline: 1.0633x; 1.0633x over previous
//
#include <hip/hip_runtime.h>

// DistanceScaledDotAttention: B=4,H=8,S=2048,D=64
//   scores = (Q K^T / 8) * dist; masked -> -1e10; softmax; ctx = P V
//   outputs: ctx [4,8,2048,64] fp32, attn [4,8,2048,2048] fp32 (concat in d_out)
//
// v4 structure (v3 with TQ=16: full 16x16 MFMA tiles, no idle lanes):
//   prep_kernel: K,V -> f16 MFMA-fragment planes in workspace (16 MiB).
//   dsda_kernel: one block = 16 q-rows of one (b,h); 32 k-tiles of 64.
//     - all 16 MFMA rows valid -> half the MFMA/VALU/VMEM instrs per output
//       vs TQ=8 (which wasted rows 8..15 of every tile).
//     - K/V fragments + dist/mask for tile kt+1 prefetched into registers.
//     - in-loop barrier is raw s_barrier + lgkmcnt(0) only (vmem prefetch
//       stays in flight across the barrier).
//     - e_smem 16x2048 f16 (64 KB), XOR-swizzled byte ^= (row&7)<<4:
//       PV ds_read_b128 is 2-way aliased = free (m136).
//     - dist/mask loads + attn stores nontemporal (touch-once stream).

typedef float v4f __attribute__((ext_vector_type(4)));
typedef _Float16 v8h __attribute__((ext_vector_type(8)));

#define SEQ 2048
#define DH  64
#define TQ  16
#define TK  64
#define NKT (SEQ / TK)   // 32
#define NBH 32
#define PLANE ((size_t)NBH * NKT * 256)   // v8h elements per fragment plane (4 MiB)

__device__ inline v8h cvt8(float4 a, float4 b) {
    v8h h;
    h[0] = (_Float16)a.x; h[1] = (_Float16)a.y; h[2] = (_Float16)a.z; h[3] = (_Float16)a.w;
    h[4] = (_Float16)b.x; h[5] = (_Float16)b.y; h[6] = (_Float16)b.z; h[7] = (_Float16)b.w;
    return h;
}

// ---- prep: build fragment planes (unchanged from v2/v3) ---------------------
// Kf0[bh][kt][tid] = { (f16)K[bh][kt*64 + 16*wave + l16][quad*8 + j] , j=0..7 }
// Kf1: d += 32.
// Vf0[bh][kt][tid] = { (f16)V[bh][kt*64 + quad*8 + j][wave*16 + l16] , j=0..7 }
// Vf1: k += 32.
__global__ __launch_bounds__(256)
void prep_kernel(const float* __restrict__ Kg, const float* __restrict__ Vg,
                 v8h* __restrict__ W)
{
    const int kt   = blockIdx.x;
    const int bh   = blockIdx.y;
    const int tid  = (int)threadIdx.x;
    const int wave = tid >> 6;
    const int lane = tid & 63;
    const int quad = lane >> 4;
    const int l16  = lane & 15;
    const int k0   = kt * TK;

    const size_t bh_off = (size_t)bh * SEQ * DH;
    const size_t fi     = ((size_t)bh * NKT + kt) * 256 + tid;

    const float* kr = Kg + bh_off + (size_t)(k0 + wave * 16 + l16) * DH + quad * 8;
    W[fi]         = cvt8(((const float4*)kr)[0], ((const float4*)kr)[1]);
    W[PLANE + fi] = cvt8(((const float4*)(kr + 32))[0], ((const float4*)(kr + 32))[1]);

    const float* vc = Vg + bh_off + (size_t)(k0 + quad * 8) * DH + wave * 16 + l16;
    v8h v0, v1;
#pragma unroll
    for (int j = 0; j < 8; ++j) {
        v0[j] = (_Float16)vc[(size_t)j * DH];
        v1[j] = (_Float16)vc[(size_t)(j + 32) * DH];
    }
    W[2 * PLANE + fi] = v0;
    W[3 * PLANE + fi] = v1;
}

// ---- main -------------------------------------------------------------------
template<bool USE_WS>
__global__ __launch_bounds__(256, 2)
void dsda_kernel(const float* __restrict__ Qg, const float* __restrict__ Kg,
                 const float* __restrict__ Vg, const float* __restrict__ distg,
                 const int* __restrict__ maskg, const v8h* __restrict__ W,
                 float* __restrict__ ctx_out, float* __restrict__ attn_out)
{
    const int qt   = blockIdx.x;    // 0..127 (fast dim: same bh streams together -> L2 reuse of frags)
    const int bh   = blockIdx.y;    // 0..31
    const int q0   = qt * TQ;
    const int tid  = (int)threadIdx.x;
    const int wave = tid >> 6;
    const int lane = tid & 63;
    const int quad = lane >> 4;
    const int l16  = lane & 15;

    // e_smem: swizzled addressing, byte(row,col) = row*4096 + ((col*2) ^ ((row&7)<<4))
    __shared__ __align__(16) _Float16 e_smem[TQ * SEQ];   // 64 KB
    __shared__ float rs[TQ];
    if (tid < TQ) rs[tid] = 0.f;

    const size_t bh_off  = (size_t)bh * SEQ;
    const float* Qb = Qg + bh_off * DH;
    const float* Kb = Kg + bh_off * DH;
    const float* Vb = Vg + bh_off * DH;
    const size_t dm_base = (bh_off + (size_t)q0) * SEQ;

    // Q A-fragments (persist): A[m=l16][k = s*32 + quad*8 + j], all 16 rows valid
    v8h aq0, aq1;
    {
        const float* qrow = Qb + (size_t)(q0 + l16) * DH;
        const float4* p0 = (const float4*)(qrow + quad * 8);
        const float4* p1 = (const float4*)(qrow + 32 + quad * 8);
        aq0 = cvt8(p0[0], p0[1]);
        aq1 = cvt8(p1[0], p1[1]);
    }

    v4f acc_pv = {0.f, 0.f, 0.f, 0.f};      // ctx acc: [row=quad*4+r][d=wave*16+l16]
    float rsum[4] = {0.f, 0.f, 0.f, 0.f};   // partials for rows quad*4+r
    const size_t fbase = (size_t)bh * NKT * 256 + tid;

#define LOAD_FRAGS(KT, B0, B1, B2, B3) do {                                   \
        const size_t fi_ = fbase + (size_t)(KT) * 256;                        \
        B0 = W[fi_]; B1 = W[PLANE + fi_];                                     \
        B2 = W[2 * PLANE + fi_]; B3 = W[3 * PLANE + fi_];                     \
    } while (0)

    // all 64 lanes: 4 rows (quad*4+r) x 1 col (k0+16w+l16) each
#define LOAD_DM(KT, DV, MV) do {                                              \
        const int kc_ = (KT) * TK + wave * 16 + l16;                          \
        _Pragma("unroll")                                                     \
        for (int r_ = 0; r_ < 4; ++r_) {                                      \
            const size_t idx_ = dm_base + (size_t)(quad * 4 + r_) * SEQ + kc_; \
            DV[r_] = __builtin_nontemporal_load(&distg[idx_]);                \
            MV[r_] = __builtin_nontemporal_load(&maskg[idx_]);                \
        }                                                                     \
    } while (0)

    if constexpr (USE_WS) {
        // ---- prologue: tile 0 in flight ----
        v8h bk0_c, bk1_c, bv0_c, bv1_c;
        float dv_c[4]; int mv_c[4];
        LOAD_FRAGS(0, bk0_c, bk1_c, bv0_c, bv1_c);
        LOAD_DM(0, dv_c, mv_c);

#pragma unroll 2
        for (int kt = 0; kt < NKT; ++kt) {
            const int k0 = kt * TK;

            // ---- prefetch tile kt+1 (clamped; values unused on last iter) ----
            const int ktn = (kt + 1 < NKT) ? kt + 1 : 0;
            v8h bk0_n, bk1_n, bv0_n, bv1_n;
            float dv_n[4]; int mv_n[4];
            LOAD_FRAGS(ktn, bk0_n, bk1_n, bv0_n, bv1_n);
            LOAD_DM(ktn, dv_n, mv_n);

            // ---- QK^T: wave w owns k-cols [k0+16w, +16) ----
            v4f accs = {0.f, 0.f, 0.f, 0.f};
            accs = __builtin_amdgcn_mfma_f32_16x16x32_f16(aq0, bk0_c, accs, 0, 0, 0);
            accs = __builtin_amdgcn_mfma_f32_16x16x32_f16(aq1, bk1_c, accs, 0, 0, 0);

            // ---- epilogue: scale, mask, exp; stash e (swizzled) + row-sums ----
            {
                const int kc = k0 + wave * 16 + l16;
#pragma unroll
                for (int r = 0; r < 4; ++r) {
                    const int row = quad * 4 + r;
                    const float sc = accs[r] * 0.125f * dv_c[r];
                    const float e  = mv_c[r] ? 0.f : __expf(sc);
                    rsum[r] += e;
                    *(_Float16*)((char*)e_smem + (row * (SEQ * 2) + ((kc * 2) ^ ((row & 7) << 4)))) = (_Float16)e;
                }
            }

            // ---- barrier: LDS visibility only (keep prefetch vmem in flight) ----
            asm volatile("s_waitcnt lgkmcnt(0)" ::: "memory");
            __builtin_amdgcn_s_barrier();
            asm volatile("" ::: "memory");

            // ---- PV: A[m=l16][k]=e (swizzled b128, 2-way = free) ----
            v8h ap0, ap1;
            {
                const int b0 = l16 * (SEQ * 2) + (((k0 + quad * 8) * 2) ^ ((l16 & 7) << 4));
                const int b1 = l16 * (SEQ * 2) + (((k0 + 32 + quad * 8) * 2) ^ ((l16 & 7) << 4));
                ap0 = *(const v8h*)((const char*)e_smem + b0);
                ap1 = *(const v8h*)((const char*)e_smem + b1);
            }
            acc_pv = __builtin_amdgcn_mfma_f32_16x16x32_f16(ap0, bv0_c, acc_pv, 0, 0, 0);
            acc_pv = __builtin_amdgcn_mfma_f32_16x16x32_f16(ap1, bv1_c, acc_pv, 0, 0, 0);

            // ---- rotate double buffer (copies elided by unroll-2) ----
            bk0_c = bk0_n; bk1_c = bk1_n; bv0_c = bv0_n; bv1_c = bv1_n;
#pragma unroll
            for (int r = 0; r < 4; ++r) { dv_c[r] = dv_n[r]; mv_c[r] = mv_n[r]; }
        }
    } else {
        // ---- fallback path (no workspace): direct loads, no pipeline ----
        for (int kt = 0; kt < NKT; ++kt) {
            const int k0 = kt * TK;
            v8h bk0, bk1, bv0, bv1;
            const float* kr = Kb + (size_t)(k0 + wave * 16 + l16) * DH + quad * 8;
            bk0 = cvt8(((const float4*)kr)[0], ((const float4*)kr)[1]);
            bk1 = cvt8(((const float4*)(kr + 32))[0], ((const float4*)(kr + 32))[1]);
            const float* vc = Vb + (size_t)(k0 + quad * 8) * DH + wave * 16 + l16;
#pragma unroll
            for (int j = 0; j < 8; ++j) {
                bv0[j] = (_Float16)vc[(size_t)j * DH];
                bv1[j] = (_Float16)vc[(size_t)(j + 32) * DH];
            }
            float dv[4]; int mv[4];
            LOAD_DM(kt, dv, mv);

            v4f accs = {0.f, 0.f, 0.f, 0.f};
            accs = __builtin_amdgcn_mfma_f32_16x16x32_f16(aq0, bk0, accs, 0, 0, 0);
            accs = __builtin_amdgcn_mfma_f32_16x16x32_f16(aq1, bk1, accs, 0, 0, 0);

            {
                const int kc = k0 + wave * 16 + l16;
#pragma unroll
                for (int r = 0; r < 4; ++r) {
                    const int row = quad * 4 + r;
                    const float sc = accs[r] * 0.125f * dv[r];
                    const float e  = mv[r] ? 0.f : __expf(sc);
                    rsum[r] += e;
                    *(_Float16*)((char*)e_smem + (row * (SEQ * 2) + ((kc * 2) ^ ((row & 7) << 4)))) = (_Float16)e;
                }
            }
            __syncthreads();

            v8h ap0, ap1;
            {
                const int b0 = l16 * (SEQ * 2) + (((k0 + quad * 8) * 2) ^ ((l16 & 7) << 4));
                const int b1 = l16 * (SEQ * 2) + (((k0 + 32 + quad * 8) * 2) ^ ((l16 & 7) << 4));
                ap0 = *(const v8h*)((const char*)e_smem + b0);
                ap1 = *(const v8h*)((const char*)e_smem + b1);
            }
            acc_pv = __builtin_amdgcn_mfma_f32_16x16x32_f16(ap0, bv0, acc_pv, 0, 0, 0);
            acc_pv = __builtin_amdgcn_mfma_f32_16x16x32_f16(ap1, bv1, acc_pv, 0, 0, 0);
        }
    }

    // ---- reduce row sums: sum over l16 within quad, then across waves ----
#pragma unroll
    for (int r = 0; r < 4; ++r) {
        float v = rsum[r];
        v += __shfl_xor(v, 1);
        v += __shfl_xor(v, 2);
        v += __shfl_xor(v, 4);
        v += __shfl_xor(v, 8);
        if (l16 == 0) atomicAdd(&rs[quad * 4 + r], v);
    }
    __syncthreads();

    // ---- context write: all 16 rows, all lanes ----
#pragma unroll
    for (int r = 0; r < 4; ++r) {
        const int row = quad * 4 + r;
        const float inv = 1.f / rs[row];
        ctx_out[(bh_off + (size_t)(q0 + row)) * DH + wave * 16 + l16] = acc_pv[r] * inv;
    }

    // ---- attn write: normalized e, nontemporal ext-vector stores ----
    {
        const int r  = tid >> 4;        // 0..15
        const int tt = tid & 15;        // 0..15
        const float invr = 1.f / rs[r];
        float* arow = attn_out + dm_base + (size_t)r * SEQ;
#pragma unroll
        for (int c = 0; c < 16; ++c) {
            const int col = c * 128 + tt * 8;
            const int b   = r * (SEQ * 2) + ((col * 2) ^ ((r & 7) << 4));
            v8h e8 = *(const v8h*)((const char*)e_smem + b);
            v4f f0, f1;
            f0[0] = (float)e8[0] * invr; f0[1] = (float)e8[1] * invr;
            f0[2] = (float)e8[2] * invr; f0[3] = (float)e8[3] * invr;
            f1[0] = (float)e8[4] * invr; f1[1] = (float)e8[5] * invr;
            f1[2] = (float)e8[6] * invr; f1[3] = (float)e8[7] * invr;
            __builtin_nontemporal_store(f0, (v4f*)(arow + col));
            __builtin_nontemporal_store(f1, (v4f*)(arow + col) + 1);
        }
    }
}

extern "C" void kernel_launch(void* const* d_in, const int* in_sizes, int n_in,
                              void* d_out, int out_size, void* d_ws, size_t ws_size,
                              hipStream_t stream) {
    const float* Q    = (const float*)d_in[0];
    const float* K    = (const float*)d_in[1];
    const float* V    = (const float*)d_in[2];
    const float* dist = (const float*)d_in[3];
    const int*   mask = (const int*)d_in[4];

    float* ctx  = (float*)d_out;                                  // 4*8*2048*64
    float* attn = (float*)d_out + (size_t)4 * 8 * 2048 * 64;      // 4*8*2048*2048

    const size_t need = 4 * PLANE * sizeof(v8h);                  // 16 MiB
    if (d_ws != nullptr && ws_size >= need) {
        hipLaunchKernelGGL(prep_kernel, dim3(NKT, NBH), dim3(256), 0, stream,
                           K, V, (v8h*)d_ws);
        hipLaunchKernelGGL((dsda_kernel<true>), dim3(SEQ / TQ, NBH), dim3(256), 0, stream,
                           Q, K, V, dist, mask, (const v8h*)d_ws, ctx, attn);
    } else {
        hipLaunchKernelGGL((dsda_kernel<false>), dim3(SEQ / TQ, NBH), dim3(256), 0, stream,
                           Q, K, V, dist, mask, (const v8h*)nullptr, ctx, attn);
    }
}